// Round 1
// baseline (691.357 us; speedup 1.0000x reference)
//
#include <hip/hip_runtime.h>
#include <math.h>

// Problem constants
#define Bsz 64
#define Tsz 4096
#define Dsz 512
#define ROWS 32                 // T-rows per block chunk
#define THREADS 512             // 8 waves
#define CHUNKS (Tsz / ROWS)     // 128

// Phase 1: each block stages a 32x512 chunk of x[b] in LDS, computes
// w_t = exp(tanh(x_t . W + bias[t])) for its 32 rows, then accumulates
//   num[b,d] += sum_t w_t * x[b,t,d]     (thread d owns column d)
//   den[b]   += sum_t w_t
// exp needs no max-subtraction: tanh bounds e to [-1,1].
__global__ __launch_bounds__(THREADS) void attn_phase1(
    const float* __restrict__ x, const float* __restrict__ W,
    const float* __restrict__ bias, float* __restrict__ num,
    float* __restrict__ den) {
  __shared__ float xs[ROWS * Dsz];   // 64 KiB -> 2 blocks/CU
  __shared__ float wrow[ROWS];

  const int tid  = threadIdx.x;
  const int lane = tid & 63;
  const int wave = tid >> 6;
  const int s = blockIdx.x;          // chunk index along T
  const int b = blockIdx.y;          // batch

  const float* src = x + ((size_t)b * Tsz + (size_t)s * ROWS) * Dsz;

  // W fragment for the dot step: lane handles cols {lane + 64k}, k=0..7
  float Wreg[8];
#pragma unroll
  for (int k = 0; k < 8; ++k) Wreg[k] = W[lane + 64 * k];

  // Stage chunk to LDS: 16384 floats, 512 threads -> 8 float4 each (coalesced)
  {
    const float4* s4 = (const float4*)src;
    float4* l4 = (float4*)xs;
#pragma unroll
    for (int it = 0; it < 8; ++it)
      l4[it * THREADS + tid] = s4[it * THREADS + tid];
  }
  __syncthreads();

  // Row dots: 8 waves x 4 rows. Lane reads cols lane+64k (bank-conflict-free),
  // butterfly shuffle-reduce across the 64-lane wave.
#pragma unroll
  for (int q = 0; q < 4; ++q) {
    const int r = wave + 8 * q;
    const float* xr = xs + r * Dsz;
    float p = 0.f;
#pragma unroll
    for (int k = 0; k < 8; ++k) p += xr[lane + 64 * k] * Wreg[k];
#pragma unroll
    for (int off = 32; off >= 1; off >>= 1) p += __shfl_xor(p, off, 64);
    if (lane == 0) {
      float e = tanhf(p + bias[s * ROWS + r]);
      wrow[r] = expf(e);
    }
  }
  __syncthreads();

  // den: wave 0 reduces the 32 weights, one atomic per block
  if (wave == 0) {
    float dv = (lane < ROWS) ? wrow[lane] : 0.f;
#pragma unroll
    for (int off = 32; off >= 1; off >>= 1) dv += __shfl_xor(dv, off, 64);
    if (lane == 0) atomicAdd(&den[b], dv);
  }

  // Weighted column sums: thread owns column d = tid.
  // xs[t*512 + tid]: consecutive lanes -> consecutive words -> conflict-free.
  float acc = 0.f;
#pragma unroll
  for (int t = 0; t < ROWS; ++t) acc += wrow[t] * xs[t * Dsz + tid];
  atomicAdd(&num[(size_t)b * Dsz + tid], acc);
}

// Phase 2: out[b,d] = num[b,d] / den[b]
__global__ __launch_bounds__(512) void attn_phase2(
    const float* __restrict__ num, const float* __restrict__ den,
    float* __restrict__ out) {
  const int i = blockIdx.x * blockDim.x + threadIdx.x;  // 0..32767
  const int b = i >> 9;
  out[i] = num[i] / den[b];
}

extern "C" void kernel_launch(void* const* d_in, const int* in_sizes, int n_in,
                              void* d_out, int out_size, void* d_ws, size_t ws_size,
                              hipStream_t stream) {
  const float* x    = (const float*)d_in[0];  // [B,T,D]
  const float* W    = (const float*)d_in[1];  // [D,1]
  const float* bias = (const float*)d_in[2];  // [T,1]
  float* num = (float*)d_ws;                  // [B*D]
  float* den = num + (size_t)Bsz * Dsz;       // [B]

  // ws is poisoned 0xAA before every launch -> zero the accumulators
  hipMemsetAsync(d_ws, 0, ((size_t)Bsz * Dsz + Bsz) * sizeof(float), stream);

  dim3 g1(CHUNKS, Bsz);
  attn_phase1<<<g1, THREADS, 0, stream>>>(x, W, bias, num, den);
  attn_phase2<<<Bsz, Dsz, 0, stream>>>(num, den, (float*)d_out);
}